// Round 9
// baseline (251.588 us; speedup 1.0000x reference)
//
#include <hip/hip_runtime.h>
#include <hip/hip_bf16.h>
#include <stdint.h>

#define DM   1024
#define SEQ  2048
#define NH   16
#define DH   64
#define FFD  4096

typedef float  f32x4  __attribute__((ext_vector_type(4)));
typedef __bf16 bf16x8 __attribute__((ext_vector_type(8)));
typedef unsigned short u16;
typedef unsigned short u16x8 __attribute__((ext_vector_type(8)));

__device__ __forceinline__ u16 f2bf(float f){
    unsigned int u = __builtin_bit_cast(unsigned int, f);
    u = u + 0x7FFFu + ((u >> 16) & 1u);   // RNE
    return (u16)(u >> 16);
}
__device__ __forceinline__ float bf2f(u16 v){
    unsigned int u = ((unsigned int)v) << 16;
    return __builtin_bit_cast(float, u);
}
__device__ __forceinline__ f32x4 zero4(){ f32x4 v; v[0]=0.f;v[1]=0.f;v[2]=0.f;v[3]=0.f; return v; }

__device__ __forceinline__ void gload_lds16(const void* g, void* l){
    __builtin_amdgcn_global_load_lds(
        (const __attribute__((address_space(1))) unsigned int*)(uintptr_t)g,
        (__attribute__((address_space(3))) unsigned int*)(uintptr_t)l,
        16, 0, 0);
}

// ---- all 4 weight transposes in ONE launch: src f32 [K][N] -> dst bf16 [N][K] ----
__global__ __launch_bounds__(256) void transall_k(const float* __restrict__ s0, u16* __restrict__ d0,
                                                  const float* __restrict__ s1, u16* __restrict__ d1,
                                                  const float* __restrict__ s2, u16* __restrict__ d2,
                                                  const float* __restrict__ s3, u16* __restrict__ d3){
    __shared__ float tile[64][65];
    const int b = blockIdx.x;
    const float* src; u16* dst; int K, N, bx, by;
    if (b < 768)      { src = s0; dst = d0; K = 1024; N = 3072; bx = b % 48;          by = b / 48; }
    else if (b < 1024){ src = s1; dst = d1; K = 1024; N = 1024; bx = (b-768) % 16;    by = (b-768) / 16; }
    else if (b < 2048){ src = s2; dst = d2; K = 1024; N = 4096; bx = (b-1024) % 64;   by = (b-1024) / 64; }
    else              { src = s3; dst = d3; K = 4096; N = 1024; bx = (b-2048) % 16;   by = (b-2048) / 16; }
    const int n0 = bx * 64, k0 = by * 64;
    const int t = threadIdx.x;
#pragma unroll
    for (int i = 0; i < 16; ++i){
        int idx = t + i * 256;
        int r = idx >> 6, c = idx & 63;
        tile[r][c] = src[(size_t)(k0 + r) * N + n0 + c];
    }
    __syncthreads();
#pragma unroll
    for (int i = 0; i < 16; ++i){
        int idx = t + i * 256;
        int r = idx >> 6, c = idx & 63;
        dst[(size_t)(n0 + r) * K + k0 + c] = f2bf(tile[c][r]);
    }
}

// ---------------- LayerNorm: fp32 in -> bf16 out, row-per-block, D=1024 ----------------
__global__ __launch_bounds__(256) void ln_k(const float* __restrict__ in,
                                            const float* __restrict__ gw,
                                            const float* __restrict__ bw,
                                            u16* __restrict__ out){
    const int row = blockIdx.x, t = threadIdx.x;
    f32x4 vv = *((const f32x4*)(in + (size_t)row * DM) + t);
    float v[4];
#pragma unroll
    for (int j = 0; j < 4; ++j) v[j] = vv[j];
    float s = 0.f, ss = 0.f;
#pragma unroll
    for (int j = 0; j < 4; ++j){ s += v[j]; ss += v[j] * v[j]; }
#pragma unroll
    for (int off = 1; off < 64; off <<= 1){
        s  += __shfl_xor(s,  off, 64);
        ss += __shfl_xor(ss, off, 64);
    }
    __shared__ float rs_[4], rss_[4];
    const int w = t >> 6;
    if ((t & 63) == 0){ rs_[w] = s; rss_[w] = ss; }
    __syncthreads();
    s  = rs_[0] + rs_[1] + rs_[2] + rs_[3];
    ss = rss_[0] + rss_[1] + rss_[2] + rss_[3];
    const float mean = s * (1.f / DM);
    const float var  = ss * (1.f / DM) - mean * mean;
    const float rstd = rsqrtf(var + 1e-5f);
#pragma unroll
    for (int j = 0; j < 4; ++j){
        int c = t * 4 + j;
        out[(size_t)row * DM + c] = f2bf((v[j] - mean) * rstd * gw[c] + bw[c]);
    }
}

// ---- GEMM: A [M][K] bf16, Bt [N][K] bf16. TMxTN tile, BK=32, global_load_lds + dbuf ----
template<int TM, int TN, int WR, int WC, int EPI>
__global__ __launch_bounds__(256) void gemm_k(const u16* __restrict__ A,
                                              const u16* __restrict__ Bt,
                                              const float* __restrict__ bias,
                                              const float* __restrict__ resid,
                                              void* __restrict__ out,
                                              int M, int N, int K){
    constexpr int MR   = TM / WR / 16;
    constexpr int NR   = TN / WC / 16;
    constexpr int AISS = (TM * 64) / 4096;
    constexpr int BISS = (TN * 64) / 4096;
    __shared__ u16 ldsA[2][TM * 32];
    __shared__ u16 ldsB[2][TN * 32];
    const int t = threadIdx.x;
    const int L = t & 63, w = t >> 6;
    const int g = L >> 4, li = L & 15;
    const int wr = w / WC, wc = w % WC;
    const int rowbase = wr * (TM / WR);
    const int colbase = wc * (TN / WC);
    const int brow = blockIdx.x * TM, bcol = blockIdx.y * TN;

    const u16* aPtr = A  + (size_t)brow * K;
    const u16* bPtr = Bt + (size_t)bcol * K;

    f32x4 acc[MR][NR];
#pragma unroll
    for (int m = 0; m < MR; ++m)
#pragma unroll
        for (int n = 0; n < NR; ++n) acc[m][n] = zero4();

    auto STAGE = [&](int buf, int ko){
#pragma unroll
        for (int i = 0; i < AISS; ++i){
            int o = i * 256 + t;
            gload_lds16(aPtr + (size_t)(o >> 2) * K + (o & 3) * 8 + ko, &ldsA[buf][o * 8]);
        }
#pragma unroll
        for (int i = 0; i < BISS; ++i){
            int o = i * 256 + t;
            gload_lds16(bPtr + (size_t)(o >> 2) * K + (o & 3) * 8 + ko, &ldsB[buf][o * 8]);
        }
    };

    const int KT = K >> 5;
    int cur = 0;
    STAGE(0, 0);
    __syncthreads();
    for (int kt = 0; kt < KT; ++kt){
        if (kt + 1 < KT) STAGE(cur ^ 1, (kt + 1) * 32);
        bf16x8 af[MR], bfr[NR];
#pragma unroll
        for (int m = 0; m < MR; ++m)
            af[m]  = *(const bf16x8*)&ldsA[cur][(rowbase + m * 16 + li) * 32 + g * 8];
#pragma unroll
        for (int n = 0; n < NR; ++n)
            bfr[n] = *(const bf16x8*)&ldsB[cur][(colbase + n * 16 + li) * 32 + g * 8];
#pragma unroll
        for (int m = 0; m < MR; ++m)
#pragma unroll
            for (int n = 0; n < NR; ++n)
                acc[m][n] = __builtin_amdgcn_mfma_f32_16x16x32_bf16(af[m], bfr[n], acc[m][n], 0, 0, 0);
        __syncthreads();
        cur ^= 1;
    }

#pragma unroll
    for (int m = 0; m < MR; ++m)
#pragma unroll
        for (int n = 0; n < NR; ++n)
#pragma unroll
            for (int r = 0; r < 4; ++r){
                const int row = brow + rowbase + m * 16 + g * 4 + r;
                const int col = bcol + colbase + n * 16 + li;
                float v = acc[m][n][r];
                if constexpr (EPI == 0){
                    ((u16*)out)[(size_t)row * N + col] = f2bf(v);
                } else if constexpr (EPI == 1){
                    v += bias[col] + resid[(size_t)row * N + col];
                    ((float*)out)[(size_t)row * N + col] = v;
                } else if constexpr (EPI == 2){
                    v += bias[col];
                    v = 0.5f * v * (1.f + erff(v * 0.70710678f));
                    ((u16*)out)[(size_t)row * N + col] = f2bf(v);
                } else {
                    v += bias[col] + resid[(size_t)row * N + col];
                    ((float*)out)[(size_t)row * N + col] = v;
                }
            }
}

// ---- RoPE + V-transpose in ONE launch ----
__global__ __launch_bounds__(256) void ropevt_k(const u16* __restrict__ qkv,
                                                u16* __restrict__ Qh, u16* __restrict__ Kh,
                                                u16* __restrict__ VT){
    __shared__ u16 tile[64][68];
    const int t = threadIdx.x;
    if (blockIdx.x < 4096){
        const int id = blockIdx.x * 256 + t;
        const int i = id & 31;
        const int s = (id >> 5) & 2047;
        const int h = id >> 16;
        const float angle = (float)s * powf(10000.f, -(float)i * (1.f / 32.f));
        float sn, cs;
        sincosf(angle, &sn, &cs);
        const size_t qoff = (size_t)s * 3072 + h * 64 + i;
        const float q1 = bf2f(qkv[qoff]),        q2 = bf2f(qkv[qoff + 32]);
        const float k1 = bf2f(qkv[qoff + 1024]), k2 = bf2f(qkv[qoff + 1024 + 32]);
        const size_t ob = ((size_t)h * SEQ + s) * 64 + i;
        Qh[ob]      = f2bf(q1 * cs - q2 * sn);
        Qh[ob + 32] = f2bf(q2 * cs + q1 * sn);
        Kh[ob]      = f2bf(k1 * cs - k2 * sn);
        Kh[ob + 32] = f2bf(k2 * cs + k1 * sn);
    } else {
        const int idx = blockIdx.x - 4096;
        const int s0 = (idx & 31) * 64, h = idx >> 5;
#pragma unroll
        for (int i = 0; i < 16; ++i){
            int id2 = t + i * 256;
            int r = id2 >> 6, c = id2 & 63;
            tile[r][c] = qkv[(size_t)(s0 + r) * 3072 + 2048 + h * 64 + c];
        }
        __syncthreads();
#pragma unroll
        for (int i = 0; i < 16; ++i){
            int id2 = t + i * 256;
            int r = id2 >> 6, c = id2 & 63;
            VT[((size_t)h * 64 + r) * SEQ + s0 + c] = tile[c][r];
        }
    }
}

// -------- split-K causal flash attention: BARRIER-FREE, wave-independent --------
// K/V fragments read directly from global (L2-resident: 512KB/head; XCD-affinity
// decode gives each XCD a 1MB KV working set). Only P goes through LDS, and it is
// wave-private (rows [w*16, w*16+16)) -> zero __syncthreads in the whole kernel.
// Flat grid 2048: bid -> {xcd=bid&7 -> h = xcd*2 + (j&1)}, LJF over qb.
#define LROW 72
#define NCHUNK 4
__global__ __launch_bounds__(256) void attn_k(const u16* __restrict__ Qh,
                                              const u16* __restrict__ Kh,
                                              const u16* __restrict__ VT,
                                              u16* __restrict__ Opart,
                                              float* __restrict__ ml){
    const int bid = blockIdx.x;
    const int xcd = bid & 7;
    const int j   = bid >> 3;            // 0..255
    const int h   = xcd * 2 + (j & 1);   // 2 heads per XCD
    const int jj  = j >> 1;              // 0..127
    const int c   = jj & 3;
    const int qb  = 31 - (jj >> 2);      // longest-job-first
    const int qbase = qb * 64;
    const int kt0 = c * 8;
    const int ktEnd = min(kt0 + 8, qb + 1);
    if (kt0 >= qb + 1) return;

    __shared__ u16 ldsP[4][16 * LROW];   // per-wave P buffer (wave-private)
    const int t = threadIdx.x, L = t & 63, w = t >> 6, g = L >> 4, li = L & 15;

    const u16* kBase = Kh + (size_t)h * SEQ * 64;
    const u16* vBase = VT + (size_t)h * 64 * SEQ;

    bf16x8 aq[2];
    {
        const u16* qrow = Qh + ((size_t)h * SEQ + qbase + w * 16 + li) * 64;
        aq[0] = *(const bf16x8*)(qrow + g * 8);
        aq[1] = *(const bf16x8*)(qrow + 32 + g * 8);
    }
    f32x4 oacc[4];
#pragma unroll
    for (int n = 0; n < 4; ++n) oacc[n] = zero4();
    float mrow[4], lrow[4];
#pragma unroll
    for (int r = 0; r < 4; ++r){ mrow[r] = -3.0e4f; lrow[r] = 0.f; }

    for (int kt = kt0; kt < ktEnd; ++kt){
        const int kkbase = kt * 64;

        // S = Q K^T — K fragments straight from global (L2)
        f32x4 sacc[4];
#pragma unroll
        for (int n = 0; n < 4; ++n) sacc[n] = zero4();
#pragma unroll
        for (int ds_ = 0; ds_ < 2; ++ds_){
#pragma unroll
            for (int n = 0; n < 4; ++n){
                const int kkl = n * 16 + li;
                bf16x8 bk = *(const bf16x8*)(kBase + (size_t)(kkbase + kkl) * 64 + ds_ * 32 + g * 8);
                sacc[n] = __builtin_amdgcn_mfma_f32_16x16x32_bf16(aq[ds_], bk, sacc[n], 0, 0, 0);
            }
        }

        const bool diag = (kkbase == qbase);
        float pv[4][4], tmax[4];
#pragma unroll
        for (int r = 0; r < 4; ++r) tmax[r] = -3.0e4f;
#pragma unroll
        for (int n = 0; n < 4; ++n)
#pragma unroll
            for (int r = 0; r < 4; ++r){
                float sv = sacc[n][r] * 0.125f;
                if (diag){
                    int kkg = kkbase + n * 16 + li;
                    int qg  = qbase + w * 16 + g * 4 + r;
                    if (kkg > qg) sv = -3.0e4f;
                }
                pv[n][r] = sv;
                tmax[r] = fmaxf(tmax[r], sv);
            }
#pragma unroll
        for (int off = 1; off < 16; off <<= 1)
#pragma unroll
            for (int r = 0; r < 4; ++r) tmax[r] = fmaxf(tmax[r], __shfl_xor(tmax[r], off, 64));

        float alpha[4], psum[4];
#pragma unroll
        for (int r = 0; r < 4; ++r){
            float nm = fmaxf(mrow[r], tmax[r]);
            alpha[r] = __expf(mrow[r] - nm);
            mrow[r] = nm;
            psum[r] = 0.f;
        }
#pragma unroll
        for (int n = 0; n < 4; ++n)
#pragma unroll
            for (int r = 0; r < 4; ++r){
                float p = __expf(pv[n][r] - mrow[r]);
                pv[n][r] = p;
                psum[r] += p;
            }
#pragma unroll
        for (int off = 1; off < 16; off <<= 1)
#pragma unroll
            for (int r = 0; r < 4; ++r) psum[r] += __shfl_xor(psum[r], off, 64);
#pragma unroll
        for (int r = 0; r < 4; ++r){
            lrow[r] = lrow[r] * alpha[r] + psum[r];
#pragma unroll
            for (int n = 0; n < 4; ++n) oacc[n][r] *= alpha[r];
        }

        // P -> per-wave LDS (wave-private; within-wave waitcnts order write->read)
#pragma unroll
        for (int n = 0; n < 4; ++n)
#pragma unroll
            for (int r = 0; r < 4; ++r){
                const int ql = g * 4 + r;
                const int kkl = n * 16 + li;
                ldsP[w][ql * LROW + kkl] = f2bf(pv[n][r]);
            }

        // O += P V — V fragments straight from global (L2)
#pragma unroll
        for (int ks = 0; ks < 2; ++ks){
            bf16x8 pa = *(const bf16x8*)(&ldsP[w][li * LROW + ks * 32 + g * 8]);
#pragma unroll
            for (int n = 0; n < 4; ++n){
                const int dv = n * 16 + li;
                bf16x8 vb = *(const bf16x8*)(vBase + (size_t)dv * SEQ + kkbase + ks * 32 + g * 8);
                oacc[n] = __builtin_amdgcn_mfma_f32_16x16x32_bf16(pa, vb, oacc[n], 0, 0, 0);
            }
        }
    }

    const size_t pb = (((size_t)(h * 32 + qb) * NCHUNK) + c) * 64;
#pragma unroll
    for (int n = 0; n < 4; ++n)
#pragma unroll
        for (int r = 0; r < 4; ++r){
            const int row = w * 16 + g * 4 + r;
            const int col = n * 16 + li;
            Opart[(pb + row) * 64 + col] = f2bf(oacc[n][r]);
        }
    if (li == 0){
#pragma unroll
        for (int r = 0; r < 4; ++r){
            const int row = w * 16 + g * 4 + r;
            ml[(pb + row) * 2]     = mrow[r];
            ml[(pb + row) * 2 + 1] = lrow[r];
        }
    }
}

// -------- combine split-K partials (bf16) -> att bf16 [S][1024] --------
__global__ __launch_bounds__(256) void combine_k(const u16* __restrict__ Opart,
                                                 const float* __restrict__ ml,
                                                 u16* __restrict__ att){
    const int qb = blockIdx.x, h = blockIdx.y;
    const int nact = ((qb * 64 + 63) >> 9) + 1;
    const int t = threadIdx.x;
    const int r = t >> 2, q4 = t & 3;
    const size_t pb = ((size_t)(h * 32 + qb) * NCHUNK) * 64;

    float mv[NCHUNK], lv[NCHUNK];
    float m = -3.0e30f;
    for (int c = 0; c < nact; ++c){
        mv[c] = ml[(pb + c * 64 + r) * 2];
        lv[c] = ml[(pb + c * 64 + r) * 2 + 1];
        m = fmaxf(m, mv[c]);
    }
    float wgt[NCHUNK], Lsum = 0.f;
    for (int c = 0; c < nact; ++c){
        wgt[c] = __expf(mv[c] - m);
        Lsum += wgt[c] * lv[c];
    }
    const float inv = 1.f / Lsum;

    float o[16];
#pragma unroll
    for (int j = 0; j < 16; ++j) o[j] = 0.f;
    for (int c = 0; c < nact; ++c){
        const u16* src = Opart + (pb + c * 64 + r) * 64 + q4 * 16;
        u16x8 a = *(const u16x8*)src;
        u16x8 b = *(const u16x8*)(src + 8);
#pragma unroll
        for (int e = 0; e < 8; ++e){
            o[e]     += wgt[c] * bf2f(a[e]);
            o[8 + e] += wgt[c] * bf2f(b[e]);
        }
    }
    const int qg = qb * 64 + r;
#pragma unroll
    for (int j = 0; j < 16; ++j){
        const int col = h * 64 + q4 * 16 + j;
        att[(size_t)qg * DM + col] = f2bf(o[j] * inv);
    }
}

extern "C" void kernel_launch(void* const* d_in, const int* in_sizes, int n_in,
                              void* d_out, int out_size, void* d_ws, size_t ws_size,
                              hipStream_t stream){
    (void)in_sizes; (void)n_in; (void)out_size; (void)ws_size;
    const float* x      = (const float*)d_in[0];
    const float* w_qkv  = (const float*)d_in[1];
    const float* w_attn = (const float*)d_in[2];
    const float* b_attn = (const float*)d_in[3];
    const float* w_ff1  = (const float*)d_in[4];
    const float* b_ff1  = (const float*)d_in[5];
    const float* w_ff2  = (const float*)d_in[6];
    const float* b_ff2  = (const float*)d_in[7];
    const float* ln1g   = (const float*)d_in[8];
    const float* ln1b   = (const float*)d_in[9];
    const float* ln2g   = (const float*)d_in[10];
    const float* ln2b   = (const float*)d_in[11];

    // 65MB workspace, liveness-scheduled.
    char* ws = (char*)d_ws;
    const size_t MB = 1u << 20;
    u16*   T1    = (u16*)(ws + 0);        // wTqkv  [3072][1024]  0-6MB   (live to gemm0)
    u16*   T2    = (u16*)(ws + 6  * MB);  // wTattn [1024][1024]  6-8MB   (live to gemm1)
    u16*   T3    = (u16*)(ws + 8  * MB);  // wTff1  [4096][1024]  8-16MB  (live to gemm2)
    u16*   T4    = (u16*)(ws + 16 * MB);  // wTff2  [1024][4096]  16-24MB (live to gemm3)
    u16*   qkv   = (u16*)(ws + 24 * MB);  // [2048][3072]         24-36MB (dead after ropevt)
    u16*   h1    = (u16*)(ws + 36 * MB);  // [2048][1024]         36-40MB (dead after gemm0)
    u16*   Qh    = (u16*)(ws + 36 * MB);  // [16][2048][64]       36-40MB (after h1 dead)
    u16*   Kh    = (u16*)(ws + 40 * MB);  // [16][2048][64]       40-44MB
    u16*   VT    = (u16*)(ws + 44 * MB);  // [16][64][2048]       44-48MB
    u16*   Opart = (u16*)(ws + 48 * MB);  // bf16 [16][32][4][64][64] 48-64MB (dead after combine)
    float* mlbuf = (float*)(ws + 64 * MB);// f32  [16][32][4][64][2]  64-65MB
    u16*   att   = (u16*)(ws + 24 * MB);  // [2048][1024]         24-28MB (qkv dead)
    float* x2    = (float*)(ws + 28 * MB);// f32 [2048][1024]     28-36MB (live to gemm3)
    u16*   h2    = (u16*)(ws + 36 * MB);  // [2048][1024]         36-40MB (Qh dead)
    u16*   ff    = (u16*)(ws + 48 * MB);  // [2048][4096]         48-64MB (Opart dead)

    transall_k<<<3072, 256, 0, stream>>>(w_qkv, T1, w_attn, T2, w_ff1, T3, w_ff2, T4);
    ln_k<<<SEQ, 256, 0, stream>>>(x, ln1g, ln1b, h1);
    gemm_k<64,128,1,4,0><<<dim3(32, 24), 256, 0, stream>>>(h1, T1, nullptr, nullptr, qkv, SEQ, 3072, 1024);
    ropevt_k<<<4608, 256, 0, stream>>>(qkv, Qh, Kh, VT);
    attn_k<<<2048, 256, 0, stream>>>(Qh, Kh, VT, Opart, mlbuf);
    combine_k<<<dim3(32, 16), 256, 0, stream>>>(Opart, mlbuf, att);
    gemm_k<64,64,2,2,1><<<dim3(32, 16), 256, 0, stream>>>(att, T2, b_attn, x, x2, SEQ, 1024, 1024);
    ln_k<<<SEQ, 256, 0, stream>>>(x2, ln2g, ln2b, h2);
    gemm_k<64,128,1,4,2><<<dim3(32, 32), 256, 0, stream>>>(h2, T3, b_ff1, nullptr, ff, SEQ, 4096, 1024);
    gemm_k<64,64,2,2,3><<<dim3(32, 16), 256, 0, stream>>>(ff, T4, b_ff2, x2, (float*)d_out, SEQ, 1024, 4096);
}

// Round 10
// 218.836 us; speedup vs baseline: 1.1497x; 1.1497x over previous
//
#include <hip/hip_runtime.h>
#include <hip/hip_bf16.h>
#include <stdint.h>

#define DM   1024
#define SEQ  2048
#define NH   16
#define DH   64
#define FFD  4096

typedef float  f32x4  __attribute__((ext_vector_type(4)));
typedef __bf16 bf16x8 __attribute__((ext_vector_type(8)));
typedef unsigned short u16;
typedef unsigned short u16x8 __attribute__((ext_vector_type(8)));

__device__ __forceinline__ u16 f2bf(float f){
    unsigned int u = __builtin_bit_cast(unsigned int, f);
    u = u + 0x7FFFu + ((u >> 16) & 1u);   // RNE
    return (u16)(u >> 16);
}
__device__ __forceinline__ float bf2f(u16 v){
    unsigned int u = ((unsigned int)v) << 16;
    return __builtin_bit_cast(float, u);
}
__device__ __forceinline__ f32x4 zero4(){ f32x4 v; v[0]=0.f;v[1]=0.f;v[2]=0.f;v[3]=0.f; return v; }

__device__ __forceinline__ void gload_lds16(const void* g, void* l){
    __builtin_amdgcn_global_load_lds(
        (const __attribute__((address_space(1))) unsigned int*)(uintptr_t)g,
        (__attribute__((address_space(3))) unsigned int*)(uintptr_t)l,
        16, 0, 0);
}

// ---- all 4 weight transposes in ONE launch: src f32 [K][N] -> dst bf16 [N][K] ----
__global__ __launch_bounds__(256) void transall_k(const float* __restrict__ s0, u16* __restrict__ d0,
                                                  const float* __restrict__ s1, u16* __restrict__ d1,
                                                  const float* __restrict__ s2, u16* __restrict__ d2,
                                                  const float* __restrict__ s3, u16* __restrict__ d3){
    __shared__ float tile[64][65];
    const int b = blockIdx.x;
    const float* src; u16* dst; int K, N, bx, by;
    if (b < 768)      { src = s0; dst = d0; K = 1024; N = 3072; bx = b % 48;          by = b / 48; }
    else if (b < 1024){ src = s1; dst = d1; K = 1024; N = 1024; bx = (b-768) % 16;    by = (b-768) / 16; }
    else if (b < 2048){ src = s2; dst = d2; K = 1024; N = 4096; bx = (b-1024) % 64;   by = (b-1024) / 64; }
    else              { src = s3; dst = d3; K = 4096; N = 1024; bx = (b-2048) % 16;   by = (b-2048) / 16; }
    const int n0 = bx * 64, k0 = by * 64;
    const int t = threadIdx.x;
#pragma unroll
    for (int i = 0; i < 16; ++i){
        int idx = t + i * 256;
        int r = idx >> 6, c = idx & 63;
        tile[r][c] = src[(size_t)(k0 + r) * N + n0 + c];
    }
    __syncthreads();
#pragma unroll
    for (int i = 0; i < 16; ++i){
        int idx = t + i * 256;
        int r = idx >> 6, c = idx & 63;
        dst[(size_t)(n0 + r) * K + k0 + c] = f2bf(tile[c][r]);
    }
}

// ---------------- LayerNorm: fp32 in -> bf16 out, row-per-block, D=1024 ----------------
__global__ __launch_bounds__(256) void ln_k(const float* __restrict__ in,
                                            const float* __restrict__ gw,
                                            const float* __restrict__ bw,
                                            u16* __restrict__ out){
    const int row = blockIdx.x, t = threadIdx.x;
    f32x4 vv = *((const f32x4*)(in + (size_t)row * DM) + t);
    float v[4];
#pragma unroll
    for (int j = 0; j < 4; ++j) v[j] = vv[j];
    float s = 0.f, ss = 0.f;
#pragma unroll
    for (int j = 0; j < 4; ++j){ s += v[j]; ss += v[j] * v[j]; }
#pragma unroll
    for (int off = 1; off < 64; off <<= 1){
        s  += __shfl_xor(s,  off, 64);
        ss += __shfl_xor(ss, off, 64);
    }
    __shared__ float rs_[4], rss_[4];
    const int w = t >> 6;
    if ((t & 63) == 0){ rs_[w] = s; rss_[w] = ss; }
    __syncthreads();
    s  = rs_[0] + rs_[1] + rs_[2] + rs_[3];
    ss = rss_[0] + rss_[1] + rss_[2] + rss_[3];
    const float mean = s * (1.f / DM);
    const float var  = ss * (1.f / DM) - mean * mean;
    const float rstd = rsqrtf(var + 1e-5f);
#pragma unroll
    for (int j = 0; j < 4; ++j){
        int c = t * 4 + j;
        out[(size_t)row * DM + c] = f2bf((v[j] - mean) * rstd * gw[c] + bw[c]);
    }
}

// ---- GEMM: A [M][K] bf16, Bt [N][K] bf16. TMxTN tile, BK=32, global_load_lds + dbuf ----
template<int TM, int TN, int WR, int WC, int EPI>
__global__ __launch_bounds__(256) void gemm_k(const u16* __restrict__ A,
                                              const u16* __restrict__ Bt,
                                              const float* __restrict__ bias,
                                              const float* __restrict__ resid,
                                              void* __restrict__ out,
                                              int M, int N, int K){
    constexpr int MR   = TM / WR / 16;
    constexpr int NR   = TN / WC / 16;
    constexpr int AISS = (TM * 64) / 4096;
    constexpr int BISS = (TN * 64) / 4096;
    __shared__ u16 ldsA[2][TM * 32];
    __shared__ u16 ldsB[2][TN * 32];
    const int t = threadIdx.x;
    const int L = t & 63, w = t >> 6;
    const int g = L >> 4, li = L & 15;
    const int wr = w / WC, wc = w % WC;
    const int rowbase = wr * (TM / WR);
    const int colbase = wc * (TN / WC);
    const int brow = blockIdx.x * TM, bcol = blockIdx.y * TN;

    const u16* aPtr = A  + (size_t)brow * K;
    const u16* bPtr = Bt + (size_t)bcol * K;

    f32x4 acc[MR][NR];
#pragma unroll
    for (int m = 0; m < MR; ++m)
#pragma unroll
        for (int n = 0; n < NR; ++n) acc[m][n] = zero4();

    auto STAGE = [&](int buf, int ko){
#pragma unroll
        for (int i = 0; i < AISS; ++i){
            int o = i * 256 + t;
            gload_lds16(aPtr + (size_t)(o >> 2) * K + (o & 3) * 8 + ko, &ldsA[buf][o * 8]);
        }
#pragma unroll
        for (int i = 0; i < BISS; ++i){
            int o = i * 256 + t;
            gload_lds16(bPtr + (size_t)(o >> 2) * K + (o & 3) * 8 + ko, &ldsB[buf][o * 8]);
        }
    };

    const int KT = K >> 5;
    int cur = 0;
    STAGE(0, 0);
    __syncthreads();
    for (int kt = 0; kt < KT; ++kt){
        if (kt + 1 < KT) STAGE(cur ^ 1, (kt + 1) * 32);
        bf16x8 af[MR], bfr[NR];
#pragma unroll
        for (int m = 0; m < MR; ++m)
            af[m]  = *(const bf16x8*)&ldsA[cur][(rowbase + m * 16 + li) * 32 + g * 8];
#pragma unroll
        for (int n = 0; n < NR; ++n)
            bfr[n] = *(const bf16x8*)&ldsB[cur][(colbase + n * 16 + li) * 32 + g * 8];
#pragma unroll
        for (int m = 0; m < MR; ++m)
#pragma unroll
            for (int n = 0; n < NR; ++n)
                acc[m][n] = __builtin_amdgcn_mfma_f32_16x16x32_bf16(af[m], bfr[n], acc[m][n], 0, 0, 0);
        __syncthreads();
        cur ^= 1;
    }

#pragma unroll
    for (int m = 0; m < MR; ++m)
#pragma unroll
        for (int n = 0; n < NR; ++n)
#pragma unroll
            for (int r = 0; r < 4; ++r){
                const int row = brow + rowbase + m * 16 + g * 4 + r;
                const int col = bcol + colbase + n * 16 + li;
                float v = acc[m][n][r];
                if constexpr (EPI == 0){
                    ((u16*)out)[(size_t)row * N + col] = f2bf(v);
                } else if constexpr (EPI == 1){
                    v += bias[col] + resid[(size_t)row * N + col];
                    ((float*)out)[(size_t)row * N + col] = v;
                } else if constexpr (EPI == 2){
                    v += bias[col];
                    v = 0.5f * v * (1.f + erff(v * 0.70710678f));
                    ((u16*)out)[(size_t)row * N + col] = f2bf(v);
                } else {
                    v += bias[col] + resid[(size_t)row * N + col];
                    ((float*)out)[(size_t)row * N + col] = v;
                }
            }
}

// ---- RoPE + V-transpose in ONE launch ----
__global__ __launch_bounds__(256) void ropevt_k(const u16* __restrict__ qkv,
                                                u16* __restrict__ Qh, u16* __restrict__ Kh,
                                                u16* __restrict__ VT){
    __shared__ u16 tile[64][68];
    const int t = threadIdx.x;
    if (blockIdx.x < 4096){
        const int id = blockIdx.x * 256 + t;
        const int i = id & 31;
        const int s = (id >> 5) & 2047;
        const int h = id >> 16;
        const float angle = (float)s * powf(10000.f, -(float)i * (1.f / 32.f));
        float sn, cs;
        sincosf(angle, &sn, &cs);
        const size_t qoff = (size_t)s * 3072 + h * 64 + i;
        const float q1 = bf2f(qkv[qoff]),        q2 = bf2f(qkv[qoff + 32]);
        const float k1 = bf2f(qkv[qoff + 1024]), k2 = bf2f(qkv[qoff + 1024 + 32]);
        const size_t ob = ((size_t)h * SEQ + s) * 64 + i;
        Qh[ob]      = f2bf(q1 * cs - q2 * sn);
        Qh[ob + 32] = f2bf(q2 * cs + q1 * sn);
        Kh[ob]      = f2bf(k1 * cs - k2 * sn);
        Kh[ob + 32] = f2bf(k2 * cs + k1 * sn);
    } else {
        const int idx = blockIdx.x - 4096;
        const int s0 = (idx & 31) * 64, h = idx >> 5;
#pragma unroll
        for (int i = 0; i < 16; ++i){
            int id2 = t + i * 256;
            int r = id2 >> 6, c = id2 & 63;
            tile[r][c] = qkv[(size_t)(s0 + r) * 3072 + 2048 + h * 64 + c];
        }
        __syncthreads();
#pragma unroll
        for (int i = 0; i < 16; ++i){
            int id2 = t + i * 256;
            int r = id2 >> 6, c = id2 & 63;
            VT[((size_t)h * 64 + r) * SEQ + s0 + c] = tile[c][r];
        }
    }
}

// -------- split-K causal flash attention (R8 structure: best measured, 71us) --------
#define LROW 72
#define NCHUNK 4
__global__ __launch_bounds__(256) void attn_k(const u16* __restrict__ Qh,
                                              const u16* __restrict__ Kh,
                                              const u16* __restrict__ VT,
                                              u16* __restrict__ Opart,
                                              float* __restrict__ ml){
    const int qb = (int)(gridDim.x - 1) - blockIdx.x;
    const int h = blockIdx.y, c = blockIdx.z;
    const int qbase = qb * 64;
    const int kt0 = c * 8;
    const int ktEnd = min(kt0 + 8, qb + 1);
    if (kt0 >= qb + 1) return;

    __shared__ u16 ldsK[64 * LROW];
    __shared__ u16 ldsV[64 * LROW];
    __shared__ u16 ldsP[64 * LROW];
    const int t = threadIdx.x, L = t & 63, w = t >> 6, g = L >> 4, li = L & 15;

    int rr_[2], ce_[2];
#pragma unroll
    for (int i = 0; i < 2; ++i){
        int o = i * 256 + t;
        rr_[i] = o >> 3; ce_[i] = (o & 7) * 8;
    }
    const u16* kBase = Kh + (size_t)h * SEQ * 64;
    const u16* vBase = VT + (size_t)h * 64 * SEQ;

    bf16x8 aq[2];
    {
        const u16* qrow = Qh + ((size_t)h * SEQ + qbase + w * 16 + li) * 64;
        aq[0] = *(const bf16x8*)(qrow + g * 8);
        aq[1] = *(const bf16x8*)(qrow + 32 + g * 8);
    }
    f32x4 oacc[4];
#pragma unroll
    for (int n = 0; n < 4; ++n) oacc[n] = zero4();
    float mrow[4], lrow[4];
#pragma unroll
    for (int r = 0; r < 4; ++r){ mrow[r] = -3.0e4f; lrow[r] = 0.f; }

    bf16x8 kr[2], vr[2];
#pragma unroll
    for (int i = 0; i < 2; ++i){
        kr[i] = *(const bf16x8*)(kBase + (size_t)(kt0 * 64 + rr_[i]) * 64 + ce_[i]);
        vr[i] = *(const bf16x8*)(vBase + (size_t)rr_[i] * SEQ + kt0 * 64 + ce_[i]);
    }
#pragma unroll
    for (int i = 0; i < 2; ++i){
        *(bf16x8*)(&ldsK[rr_[i] * LROW + ce_[i]]) = kr[i];
        *(bf16x8*)(&ldsV[rr_[i] * LROW + ce_[i]]) = vr[i];
    }
    __syncthreads();

    for (int kt = kt0; kt < ktEnd; ++kt){
        const int kkbase = kt * 64;
        const bool more = (kt + 1 < ktEnd);
        if (more){
            const int nb = (kt + 1) * 64;
#pragma unroll
            for (int i = 0; i < 2; ++i){
                kr[i] = *(const bf16x8*)(kBase + (size_t)(nb + rr_[i]) * 64 + ce_[i]);
                vr[i] = *(const bf16x8*)(vBase + (size_t)rr_[i] * SEQ + nb + ce_[i]);
            }
        }

        f32x4 sacc[4];
#pragma unroll
        for (int n = 0; n < 4; ++n) sacc[n] = zero4();
#pragma unroll
        for (int ds_ = 0; ds_ < 2; ++ds_){
#pragma unroll
            for (int n = 0; n < 4; ++n){
                const int kkl = n * 16 + li;
                bf16x8 bk = *(const bf16x8*)(&ldsK[kkl * LROW + ds_ * 32 + g * 8]);
                sacc[n] = __builtin_amdgcn_mfma_f32_16x16x32_bf16(aq[ds_], bk, sacc[n], 0, 0, 0);
            }
        }

        const bool diag = (kkbase == qbase);
        float pv[4][4], tmax[4];
#pragma unroll
        for (int r = 0; r < 4; ++r) tmax[r] = -3.0e4f;
#pragma unroll
        for (int n = 0; n < 4; ++n)
#pragma unroll
            for (int r = 0; r < 4; ++r){
                float sv = sacc[n][r] * 0.125f;
                if (diag){
                    int kkg = kkbase + n * 16 + li;
                    int qg  = qbase + w * 16 + g * 4 + r;
                    if (kkg > qg) sv = -3.0e4f;
                }
                pv[n][r] = sv;
                tmax[r] = fmaxf(tmax[r], sv);
            }
#pragma unroll
        for (int off = 1; off < 16; off <<= 1)
#pragma unroll
            for (int r = 0; r < 4; ++r) tmax[r] = fmaxf(tmax[r], __shfl_xor(tmax[r], off, 64));

        float alpha[4], psum[4];
#pragma unroll
        for (int r = 0; r < 4; ++r){
            float nm = fmaxf(mrow[r], tmax[r]);
            alpha[r] = __expf(mrow[r] - nm);
            mrow[r] = nm;
            psum[r] = 0.f;
        }
#pragma unroll
        for (int n = 0; n < 4; ++n)
#pragma unroll
            for (int r = 0; r < 4; ++r){
                float p = __expf(pv[n][r] - mrow[r]);
                pv[n][r] = p;
                psum[r] += p;
            }
#pragma unroll
        for (int off = 1; off < 16; off <<= 1)
#pragma unroll
            for (int r = 0; r < 4; ++r) psum[r] += __shfl_xor(psum[r], off, 64);
#pragma unroll
        for (int r = 0; r < 4; ++r){
            lrow[r] = lrow[r] * alpha[r] + psum[r];
#pragma unroll
            for (int n = 0; n < 4; ++n) oacc[n][r] *= alpha[r];
        }

#pragma unroll
        for (int n = 0; n < 4; ++n)
#pragma unroll
            for (int r = 0; r < 4; ++r){
                const int ql = w * 16 + g * 4 + r;
                const int kkl = n * 16 + li;
                ldsP[ql * LROW + kkl] = f2bf(pv[n][r]);
            }

#pragma unroll
        for (int ks = 0; ks < 2; ++ks){
            const int qa = w * 16 + li;
            bf16x8 pa = *(const bf16x8*)(ldsP + qa * LROW + ks * 32 + g * 8);
#pragma unroll
            for (int n = 0; n < 4; ++n){
                const int dv = n * 16 + li;
                bf16x8 vb = *(const bf16x8*)(&ldsV[dv * LROW + ks * 32 + g * 8]);
                oacc[n] = __builtin_amdgcn_mfma_f32_16x16x32_bf16(pa, vb, oacc[n], 0, 0, 0);
            }
        }

        __syncthreads();
        if (more){
#pragma unroll
            for (int i = 0; i < 2; ++i){
                *(bf16x8*)(&ldsK[rr_[i] * LROW + ce_[i]]) = kr[i];
                *(bf16x8*)(&ldsV[rr_[i] * LROW + ce_[i]]) = vr[i];
            }
            __syncthreads();
        }
    }

    const size_t pb = (((size_t)(h * 32 + qb) * NCHUNK) + c) * 64;
#pragma unroll
    for (int n = 0; n < 4; ++n)
#pragma unroll
        for (int r = 0; r < 4; ++r){
            const int row = w * 16 + g * 4 + r;
            const int col = n * 16 + li;
            Opart[(pb + row) * 64 + col] = f2bf(oacc[n][r]);
        }
    if (li == 0){
#pragma unroll
        for (int r = 0; r < 4; ++r){
            const int row = w * 16 + g * 4 + r;
            ml[(pb + row) * 2]     = mrow[r];
            ml[(pb + row) * 2 + 1] = lrow[r];
        }
    }
}

// -------- combine split-K partials (bf16) -> att bf16 [S][1024] --------
__global__ __launch_bounds__(256) void combine_k(const u16* __restrict__ Opart,
                                                 const float* __restrict__ ml,
                                                 u16* __restrict__ att){
    const int qb = blockIdx.x, h = blockIdx.y;
    const int nact = ((qb * 64 + 63) >> 9) + 1;
    const int t = threadIdx.x;
    const int r = t >> 2, q4 = t & 3;
    const size_t pb = ((size_t)(h * 32 + qb) * NCHUNK) * 64;

    float mv[NCHUNK], lv[NCHUNK];
    float m = -3.0e30f;
    for (int c = 0; c < nact; ++c){
        mv[c] = ml[(pb + c * 64 + r) * 2];
        lv[c] = ml[(pb + c * 64 + r) * 2 + 1];
        m = fmaxf(m, mv[c]);
    }
    float wgt[NCHUNK], Lsum = 0.f;
    for (int c = 0; c < nact; ++c){
        wgt[c] = __expf(mv[c] - m);
        Lsum += wgt[c] * lv[c];
    }
    const float inv = 1.f / Lsum;

    float o[16];
#pragma unroll
    for (int j = 0; j < 16; ++j) o[j] = 0.f;
    for (int c = 0; c < nact; ++c){
        const u16* src = Opart + (pb + c * 64 + r) * 64 + q4 * 16;
        u16x8 a = *(const u16x8*)src;
        u16x8 b = *(const u16x8*)(src + 8);
#pragma unroll
        for (int e = 0; e < 8; ++e){
            o[e]     += wgt[c] * bf2f(a[e]);
            o[8 + e] += wgt[c] * bf2f(b[e]);
        }
    }
    const int qg = qb * 64 + r;
#pragma unroll
    for (int j = 0; j < 16; ++j){
        const int col = h * 64 + q4 * 16 + j;
        att[(size_t)qg * DM + col] = f2bf(o[j] * inv);
    }
}

extern "C" void kernel_launch(void* const* d_in, const int* in_sizes, int n_in,
                              void* d_out, int out_size, void* d_ws, size_t ws_size,
                              hipStream_t stream){
    (void)in_sizes; (void)n_in; (void)out_size; (void)ws_size;
    const float* x      = (const float*)d_in[0];
    const float* w_qkv  = (const float*)d_in[1];
    const float* w_attn = (const float*)d_in[2];
    const float* b_attn = (const float*)d_in[3];
    const float* w_ff1  = (const float*)d_in[4];
    const float* b_ff1  = (const float*)d_in[5];
    const float* w_ff2  = (const float*)d_in[6];
    const float* b_ff2  = (const float*)d_in[7];
    const float* ln1g   = (const float*)d_in[8];
    const float* ln1b   = (const float*)d_in[9];
    const float* ln2g   = (const float*)d_in[10];
    const float* ln2b   = (const float*)d_in[11];

    // 65MB workspace, liveness-scheduled.
    char* ws = (char*)d_ws;
    const size_t MB = 1u << 20;
    u16*   T1    = (u16*)(ws + 0);        // wTqkv  [3072][1024]  0-6MB   (live to gemm0)
    u16*   T2    = (u16*)(ws + 6  * MB);  // wTattn [1024][1024]  6-8MB   (live to gemm1)
    u16*   T3    = (u16*)(ws + 8  * MB);  // wTff1  [4096][1024]  8-16MB  (live to gemm2)
    u16*   T4    = (u16*)(ws + 16 * MB);  // wTff2  [1024][4096]  16-24MB (live to gemm3)
    u16*   qkv   = (u16*)(ws + 24 * MB);  // [2048][3072]         24-36MB (dead after ropevt)
    u16*   h1    = (u16*)(ws + 36 * MB);  // [2048][1024]         36-40MB (dead after gemm0)
    u16*   Qh    = (u16*)(ws + 36 * MB);  // [16][2048][64]       36-40MB (after h1 dead)
    u16*   Kh    = (u16*)(ws + 40 * MB);  // [16][2048][64]       40-44MB
    u16*   VT    = (u16*)(ws + 44 * MB);  // [16][64][2048]       44-48MB
    u16*   Opart = (u16*)(ws + 48 * MB);  // bf16 [16][32][4][64][64] 48-64MB (dead after combine)
    float* mlbuf = (float*)(ws + 64 * MB);// f32  [16][32][4][64][2]  64-65MB
    u16*   att   = (u16*)(ws + 24 * MB);  // [2048][1024]         24-28MB (qkv dead)
    float* x2    = (float*)(ws + 28 * MB);// f32 [2048][1024]     28-36MB (live to gemm3)
    u16*   h2    = (u16*)(ws + 36 * MB);  // [2048][1024]         36-40MB (Qh dead)
    u16*   ff    = (u16*)(ws + 48 * MB);  // [2048][4096]         48-64MB (Opart dead)

    transall_k<<<3072, 256, 0, stream>>>(w_qkv, T1, w_attn, T2, w_ff1, T3, w_ff2, T4);
    ln_k<<<SEQ, 256, 0, stream>>>(x, ln1g, ln1b, h1);
    gemm_k<128,128,2,2,0><<<dim3(16, 24), 256, 0, stream>>>(h1, T1, nullptr, nullptr, qkv, SEQ, 3072, 1024);
    ropevt_k<<<4608, 256, 0, stream>>>(qkv, Qh, Kh, VT);
    attn_k<<<dim3(32, 16, NCHUNK), 256, 0, stream>>>(Qh, Kh, VT, Opart, mlbuf);
    combine_k<<<dim3(32, 16), 256, 0, stream>>>(Opart, mlbuf, att);
    gemm_k<64,64,2,2,1><<<dim3(32, 16), 256, 0, stream>>>(att, T2, b_attn, x, x2, SEQ, 1024, 1024);
    ln_k<<<SEQ, 256, 0, stream>>>(x2, ln2g, ln2b, h2);
    gemm_k<128,128,2,2,2><<<dim3(16, 32), 256, 0, stream>>>(h2, T3, b_ff1, nullptr, ff, SEQ, 4096, 1024);
    gemm_k<128,64,2,2,3><<<dim3(16, 16), 256, 0, stream>>>(ff, T4, b_ff2, x2, (float*)d_out, SEQ, 1024, 4096);
}

// Round 11
// 207.173 us; speedup vs baseline: 1.2144x; 1.0563x over previous
//
#include <hip/hip_runtime.h>
#include <hip/hip_bf16.h>
#include <stdint.h>

#define DM   1024
#define SEQ  2048
#define NH   16
#define DH   64
#define FFD  4096

typedef float  f32x4  __attribute__((ext_vector_type(4)));
typedef __bf16 bf16x8 __attribute__((ext_vector_type(8)));
typedef unsigned short u16;
typedef unsigned short u16x8 __attribute__((ext_vector_type(8)));

__device__ __forceinline__ u16 f2bf(float f){
    unsigned int u = __builtin_bit_cast(unsigned int, f);
    u = u + 0x7FFFu + ((u >> 16) & 1u);   // RNE
    return (u16)(u >> 16);
}
__device__ __forceinline__ float bf2f(u16 v){
    unsigned int u = ((unsigned int)v) << 16;
    return __builtin_bit_cast(float, u);
}
__device__ __forceinline__ f32x4 zero4(){ f32x4 v; v[0]=0.f;v[1]=0.f;v[2]=0.f;v[3]=0.f; return v; }

__device__ __forceinline__ void gload_lds16(const void* g, void* l){
    __builtin_amdgcn_global_load_lds(
        (const __attribute__((address_space(1))) unsigned int*)(uintptr_t)g,
        (__attribute__((address_space(3))) unsigned int*)(uintptr_t)l,
        16, 0, 0);
}

// ---- all 4 weight transposes in ONE launch: src f32 [K][N] -> dst bf16 [N][K] ----
__global__ __launch_bounds__(256) void transall_k(const float* __restrict__ s0, u16* __restrict__ d0,
                                                  const float* __restrict__ s1, u16* __restrict__ d1,
                                                  const float* __restrict__ s2, u16* __restrict__ d2,
                                                  const float* __restrict__ s3, u16* __restrict__ d3){
    __shared__ float tile[64][65];
    const int b = blockIdx.x;
    const float* src; u16* dst; int K, N, bx, by;
    if (b < 768)      { src = s0; dst = d0; K = 1024; N = 3072; bx = b % 48;          by = b / 48; }
    else if (b < 1024){ src = s1; dst = d1; K = 1024; N = 1024; bx = (b-768) % 16;    by = (b-768) / 16; }
    else if (b < 2048){ src = s2; dst = d2; K = 1024; N = 4096; bx = (b-1024) % 64;   by = (b-1024) / 64; }
    else              { src = s3; dst = d3; K = 4096; N = 1024; bx = (b-2048) % 16;   by = (b-2048) / 16; }
    const int n0 = bx * 64, k0 = by * 64;
    const int t = threadIdx.x;
#pragma unroll
    for (int i = 0; i < 16; ++i){
        int idx = t + i * 256;
        int r = idx >> 6, c = idx & 63;
        tile[r][c] = src[(size_t)(k0 + r) * N + n0 + c];
    }
    __syncthreads();
#pragma unroll
    for (int i = 0; i < 16; ++i){
        int idx = t + i * 256;
        int r = idx >> 6, c = idx & 63;
        dst[(size_t)(n0 + r) * K + k0 + c] = f2bf(tile[c][r]);
    }
}

// ---------------- LayerNorm: fp32 in -> bf16 out, row-per-block, D=1024 ----------------
__global__ __launch_bounds__(256) void ln_k(const float* __restrict__ in,
                                            const float* __restrict__ gw,
                                            const float* __restrict__ bw,
                                            u16* __restrict__ out){
    const int row = blockIdx.x, t = threadIdx.x;
    f32x4 vv = *((const f32x4*)(in + (size_t)row * DM) + t);
    float v[4];
#pragma unroll
    for (int j = 0; j < 4; ++j) v[j] = vv[j];
    float s = 0.f, ss = 0.f;
#pragma unroll
    for (int j = 0; j < 4; ++j){ s += v[j]; ss += v[j] * v[j]; }
#pragma unroll
    for (int off = 1; off < 64; off <<= 1){
        s  += __shfl_xor(s,  off, 64);
        ss += __shfl_xor(ss, off, 64);
    }
    __shared__ float rs_[4], rss_[4];
    const int w = t >> 6;
    if ((t & 63) == 0){ rs_[w] = s; rss_[w] = ss; }
    __syncthreads();
    s  = rs_[0] + rs_[1] + rs_[2] + rs_[3];
    ss = rss_[0] + rss_[1] + rss_[2] + rss_[3];
    const float mean = s * (1.f / DM);
    const float var  = ss * (1.f / DM) - mean * mean;
    const float rstd = rsqrtf(var + 1e-5f);
#pragma unroll
    for (int j = 0; j < 4; ++j){
        int c = t * 4 + j;
        out[(size_t)row * DM + c] = f2bf((v[j] - mean) * rstd * gw[c] + bw[c]);
    }
}

// ---- GEMM: A [M][K] bf16, Bt [N][K] bf16. TMxTN tile, BK=32, global_load_lds + dbuf ----
// EPI: 1 = +bias +fp32 residual, fp32 out (attn out-proj -> x2)
//      2 = +bias, exact GELU, bf16 out (FF1)
//      3 = +bias +fp32 residual, fp32 out (FF2 -> d_out)
//      4 = QKV fused epilogue: RoPE -> Qh/Kh, V -> VT via LDS transpose.
//          Requires TN=128, WR=2, WC=2 (one head per wave).
template<int TM, int TN, int WR, int WC, int EPI>
__global__ __launch_bounds__(256) void gemm_k(const u16* __restrict__ A,
                                              const u16* __restrict__ Bt,
                                              const float* __restrict__ bias,
                                              const float* __restrict__ resid,
                                              void* __restrict__ out,
                                              u16* __restrict__ qout,
                                              u16* __restrict__ kout,
                                              u16* __restrict__ vout,
                                              int M, int N, int K){
    constexpr int MR   = TM / WR / 16;
    constexpr int NR   = TN / WC / 16;
    constexpr int AISS = (TM * 64) / 4096;
    constexpr int BISS = (TN * 64) / 4096;
    __shared__ u16 ldsAll[2 * TM * 32 + 2 * TN * 32];
    u16* ldsA = ldsAll;
    u16* ldsB = ldsAll + 2 * TM * 32;
    const int t = threadIdx.x;
    const int L = t & 63, w = t >> 6;
    const int g = L >> 4, li = L & 15;
    const int wr = w / WC, wc = w % WC;
    const int rowbase = wr * (TM / WR);
    const int colbase = wc * (TN / WC);
    const int brow = blockIdx.x * TM, bcol = blockIdx.y * TN;

    const u16* aPtr = A  + (size_t)brow * K;
    const u16* bPtr = Bt + (size_t)bcol * K;

    f32x4 acc[MR][NR];
#pragma unroll
    for (int m = 0; m < MR; ++m)
#pragma unroll
        for (int n = 0; n < NR; ++n) acc[m][n] = zero4();

    auto STAGE = [&](int buf, int ko){
#pragma unroll
        for (int i = 0; i < AISS; ++i){
            int o = i * 256 + t;
            gload_lds16(aPtr + (size_t)(o >> 2) * K + (o & 3) * 8 + ko, &ldsA[buf * TM * 32 + o * 8]);
        }
#pragma unroll
        for (int i = 0; i < BISS; ++i){
            int o = i * 256 + t;
            gload_lds16(bPtr + (size_t)(o >> 2) * K + (o & 3) * 8 + ko, &ldsB[buf * TN * 32 + o * 8]);
        }
    };

    const int KT = K >> 5;
    int cur = 0;
    STAGE(0, 0);
    __syncthreads();
    for (int kt = 0; kt < KT; ++kt){
        if (kt + 1 < KT) STAGE(cur ^ 1, (kt + 1) * 32);
        bf16x8 af[MR], bfr[NR];
#pragma unroll
        for (int m = 0; m < MR; ++m)
            af[m]  = *(const bf16x8*)&ldsA[cur * TM * 32 + (rowbase + m * 16 + li) * 32 + g * 8];
#pragma unroll
        for (int n = 0; n < NR; ++n)
            bfr[n] = *(const bf16x8*)&ldsB[cur * TN * 32 + (colbase + n * 16 + li) * 32 + g * 8];
#pragma unroll
        for (int m = 0; m < MR; ++m)
#pragma unroll
            for (int n = 0; n < NR; ++n)
                acc[m][n] = __builtin_amdgcn_mfma_f32_16x16x32_bf16(af[m], bfr[n], acc[m][n], 0, 0, 0);
        __syncthreads();
        cur ^= 1;
    }

    if constexpr (EPI == 4){
        // colabs is wave-uniform, multiple of 64; all waves of a block share `part`.
        const int colabs = bcol + colbase;
        const int part = colabs >> 10;          // 0=Q, 1=K, 2=V
        if (part < 2){
            u16* dst = (part == 0) ? qout : kout;
            const int h = (colabs >> 6) & 15;
            float freq[2];
#pragma unroll
            for (int n = 0; n < 2; ++n)
                freq[n] = powf(10000.f, -(float)(n * 16 + li) * (1.f / 32.f));
#pragma unroll
            for (int m = 0; m < MR; ++m)
#pragma unroll
                for (int r = 0; r < 4; ++r){
                    const int srow = brow + rowbase + m * 16 + g * 4 + r;
                    const size_t rb = ((size_t)h * SEQ + srow) * 64;
#pragma unroll
                    for (int n = 0; n < 2; ++n){
                        const int i = n * 16 + li;
                        float lo = acc[m][n][r], hi = acc[m][n + 2][r];
                        float sn, cs;
                        sincosf((float)srow * freq[n], &sn, &cs);
                        dst[rb + i]      = f2bf(lo * cs - hi * sn);
                        dst[rb + i + 32] = f2bf(hi * cs + lo * sn);
                    }
                }
        } else {
            // V: transpose 64x128 tile through LDS -> VT [h][dv][s]
            u16* tileT = ldsAll;                 // 128*72 u16 = 18KB <= 24KB
            __syncthreads();                     // staging reads done (loop over)
#pragma unroll
            for (int m = 0; m < MR; ++m)
#pragma unroll
                for (int n = 0; n < NR; ++n)
#pragma unroll
                    for (int r = 0; r < 4; ++r){
                        const int row = rowbase + m * 16 + g * 4 + r;   // s-local 0..63
                        const int col = colbase + n * 16 + li;          // dv-local 0..127
                        tileT[col * 72 + row] = f2bf(acc[m][n][r]);
                    }
            __syncthreads();
            const int dv = t >> 1, half = t & 1;
            const int habs = ((bcol + dv) >> 6) & 15;
            const int dvl = dv & 63;
            u16* vrow = vout + ((size_t)habs * 64 + dvl) * SEQ + brow + half * 32;
#pragma unroll
            for (int j = 0; j < 4; ++j)
                *(u16x8*)(vrow + j * 8) = *(const u16x8*)&tileT[dv * 72 + half * 32 + j * 8];
        }
        return;
    }

#pragma unroll
    for (int m = 0; m < MR; ++m)
#pragma unroll
        for (int n = 0; n < NR; ++n)
#pragma unroll
            for (int r = 0; r < 4; ++r){
                const int row = brow + rowbase + m * 16 + g * 4 + r;
                const int col = bcol + colbase + n * 16 + li;
                float v = acc[m][n][r];
                if constexpr (EPI == 1){
                    v += bias[col] + resid[(size_t)row * N + col];
                    ((float*)out)[(size_t)row * N + col] = v;
                } else if constexpr (EPI == 2){
                    v += bias[col];
                    v = 0.5f * v * (1.f + erff(v * 0.70710678f));
                    ((u16*)out)[(size_t)row * N + col] = f2bf(v);
                } else {
                    v += bias[col] + resid[(size_t)row * N + col];
                    ((float*)out)[(size_t)row * N + col] = v;
                }
            }
}

// -------- split-K causal flash attention (R6 structure — best measured) --------
#define LROW 72
#define NCHUNK 4
__global__ __launch_bounds__(256) void attn_k(const u16* __restrict__ Qh,
                                              const u16* __restrict__ Kh,
                                              const u16* __restrict__ VT,
                                              u16* __restrict__ Opart,
                                              float* __restrict__ ml){
    const int qb = blockIdx.x, h = blockIdx.y, c = blockIdx.z;
    const int qbase = qb * 64;
    const int kt0 = c * 8;
    const int ktEnd = min(kt0 + 8, qb + 1);
    if (kt0 >= qb + 1) return;

    __shared__ u16 ldsK[64 * LROW];
    __shared__ u16 ldsV[64 * LROW];
    __shared__ u16 ldsP[64 * LROW];
    const int t = threadIdx.x, L = t & 63, w = t >> 6, g = L >> 4, li = L & 15;

    bf16x8 aq[2];
    {
        const u16* qrow = Qh + ((size_t)h * SEQ + qbase + w * 16 + li) * 64;
        aq[0] = *(const bf16x8*)(qrow + g * 8);
        aq[1] = *(const bf16x8*)(qrow + 32 + g * 8);
    }
    f32x4 oacc[4];
#pragma unroll
    for (int n = 0; n < 4; ++n) oacc[n] = zero4();
    float mrow[4], lrow[4];
#pragma unroll
    for (int r = 0; r < 4; ++r){ mrow[r] = -3.0e4f; lrow[r] = 0.f; }

    for (int kt = kt0; kt < ktEnd; ++kt){
        const int kkbase = kt * 64;
        bf16x8 kreg[2], vreg[2];
        int rr_[2], ce_[2];
#pragma unroll
        for (int i = 0; i < 2; ++i){
            int o = i * 256 + t;
            rr_[i] = o >> 3; ce_[i] = (o & 7) * 8;
            kreg[i] = *(const bf16x8*)(Kh + ((size_t)h * SEQ + kkbase + rr_[i]) * 64 + ce_[i]);
            vreg[i] = *(const bf16x8*)(VT + ((size_t)h * 64 + rr_[i]) * SEQ + kkbase + ce_[i]);
        }
#pragma unroll
        for (int i = 0; i < 2; ++i){
            *(bf16x8*)(&ldsK[rr_[i] * LROW + ce_[i]]) = kreg[i];
            *(bf16x8*)(&ldsV[rr_[i] * LROW + ce_[i]]) = vreg[i];
        }
        __syncthreads();

        f32x4 sacc[4];
#pragma unroll
        for (int n = 0; n < 4; ++n) sacc[n] = zero4();
#pragma unroll
        for (int ds_ = 0; ds_ < 2; ++ds_){
#pragma unroll
            for (int n = 0; n < 4; ++n){
                const int kkl = n * 16 + li;
                bf16x8 bk = *(const bf16x8*)(&ldsK[kkl * LROW + ds_ * 32 + g * 8]);
                sacc[n] = __builtin_amdgcn_mfma_f32_16x16x32_bf16(aq[ds_], bk, sacc[n], 0, 0, 0);
            }
        }

        const bool diag = (kkbase == qbase);
        float pv[4][4], tmax[4];
#pragma unroll
        for (int r = 0; r < 4; ++r) tmax[r] = -3.0e4f;
#pragma unroll
        for (int n = 0; n < 4; ++n)
#pragma unroll
            for (int r = 0; r < 4; ++r){
                float sv = sacc[n][r] * 0.125f;
                if (diag){
                    int kkg = kkbase + n * 16 + li;
                    int qg  = qbase + w * 16 + g * 4 + r;
                    if (kkg > qg) sv = -3.0e4f;
                }
                pv[n][r] = sv;
                tmax[r] = fmaxf(tmax[r], sv);
            }
#pragma unroll
        for (int off = 1; off < 16; off <<= 1)
#pragma unroll
            for (int r = 0; r < 4; ++r) tmax[r] = fmaxf(tmax[r], __shfl_xor(tmax[r], off, 64));

        float alpha[4], psum[4];
#pragma unroll
        for (int r = 0; r < 4; ++r){
            float nm = fmaxf(mrow[r], tmax[r]);
            alpha[r] = __expf(mrow[r] - nm);
            mrow[r] = nm;
            psum[r] = 0.f;
        }
#pragma unroll
        for (int n = 0; n < 4; ++n)
#pragma unroll
            for (int r = 0; r < 4; ++r){
                float p = __expf(pv[n][r] - mrow[r]);
                pv[n][r] = p;
                psum[r] += p;
            }
#pragma unroll
        for (int off = 1; off < 16; off <<= 1)
#pragma unroll
            for (int r = 0; r < 4; ++r) psum[r] += __shfl_xor(psum[r], off, 64);
#pragma unroll
        for (int r = 0; r < 4; ++r){
            lrow[r] = lrow[r] * alpha[r] + psum[r];
#pragma unroll
            for (int n = 0; n < 4; ++n) oacc[n][r] *= alpha[r];
        }

#pragma unroll
        for (int n = 0; n < 4; ++n)
#pragma unroll
            for (int r = 0; r < 4; ++r){
                const int ql = w * 16 + g * 4 + r;
                const int kkl = n * 16 + li;
                ldsP[ql * LROW + kkl] = f2bf(pv[n][r]);
            }
        __syncthreads();

#pragma unroll
        for (int ks = 0; ks < 2; ++ks){
            const int qa = w * 16 + li;
            bf16x8 pa = *(const bf16x8*)(ldsP + qa * LROW + ks * 32 + g * 8);
#pragma unroll
            for (int n = 0; n < 4; ++n){
                const int dv = n * 16 + li;
                bf16x8 vb = *(const bf16x8*)(&ldsV[dv * LROW + ks * 32 + g * 8]);
                oacc[n] = __builtin_amdgcn_mfma_f32_16x16x32_bf16(pa, vb, oacc[n], 0, 0, 0);
            }
        }
        __syncthreads();
    }

    const size_t pb = (((size_t)(h * 32 + qb) * NCHUNK) + c) * 64;
#pragma unroll
    for (int n = 0; n < 4; ++n)
#pragma unroll
        for (int r = 0; r < 4; ++r){
            const int row = w * 16 + g * 4 + r;
            const int col = n * 16 + li;
            Opart[(pb + row) * 64 + col] = f2bf(oacc[n][r]);
        }
    if (li == 0){
#pragma unroll
        for (int r = 0; r < 4; ++r){
            const int row = w * 16 + g * 4 + r;
            ml[(pb + row) * 2]     = mrow[r];
            ml[(pb + row) * 2 + 1] = lrow[r];
        }
    }
}

// -------- combine split-K partials (bf16) -> att bf16 [S][1024] --------
__global__ __launch_bounds__(256) void combine_k(const u16* __restrict__ Opart,
                                                 const float* __restrict__ ml,
                                                 u16* __restrict__ att){
    const int qb = blockIdx.x, h = blockIdx.y;
    const int nact = ((qb * 64 + 63) >> 9) + 1;
    const int t = threadIdx.x;
    const int r = t >> 2, q4 = t & 3;
    const size_t pb = ((size_t)(h * 32 + qb) * NCHUNK) * 64;

    float mv[NCHUNK], lv[NCHUNK];
    float m = -3.0e30f;
    for (int c = 0; c < nact; ++c){
        mv[c] = ml[(pb + c * 64 + r) * 2];
        lv[c] = ml[(pb + c * 64 + r) * 2 + 1];
        m = fmaxf(m, mv[c]);
    }
    float wgt[NCHUNK], Lsum = 0.f;
    for (int c = 0; c < nact; ++c){
        wgt[c] = __expf(mv[c] - m);
        Lsum += wgt[c] * lv[c];
    }
    const float inv = 1.f / Lsum;

    float o[16];
#pragma unroll
    for (int j = 0; j < 16; ++j) o[j] = 0.f;
    for (int c = 0; c < nact; ++c){
        const u16* src = Opart + (pb + c * 64 + r) * 64 + q4 * 16;
        u16x8 a = *(const u16x8*)src;
        u16x8 b = *(const u16x8*)(src + 8);
#pragma unroll
        for (int e = 0; e < 8; ++e){
            o[e]     += wgt[c] * bf2f(a[e]);
            o[8 + e] += wgt[c] * bf2f(b[e]);
        }
    }
    const int qg = qb * 64 + r;
#pragma unroll
    for (int j = 0; j < 16; ++j){
        const int col = h * 64 + q4 * 16 + j;
        att[(size_t)qg * DM + col] = f2bf(o[j] * inv);
    }
}

extern "C" void kernel_launch(void* const* d_in, const int* in_sizes, int n_in,
                              void* d_out, int out_size, void* d_ws, size_t ws_size,
                              hipStream_t stream){
    (void)in_sizes; (void)n_in; (void)out_size; (void)ws_size;
    const float* x      = (const float*)d_in[0];
    const float* w_qkv  = (const float*)d_in[1];
    const float* w_attn = (const float*)d_in[2];
    const float* b_attn = (const float*)d_in[3];
    const float* w_ff1  = (const float*)d_in[4];
    const float* b_ff1  = (const float*)d_in[5];
    const float* w_ff2  = (const float*)d_in[6];
    const float* b_ff2  = (const float*)d_in[7];
    const float* ln1g   = (const float*)d_in[8];
    const float* ln1b   = (const float*)d_in[9];
    const float* ln2g   = (const float*)d_in[10];
    const float* ln2b   = (const float*)d_in[11];

    // 57MB workspace, liveness-scheduled (qkv intermediate eliminated).
    char* ws = (char*)d_ws;
    const size_t MB = 1u << 20;
    u16*   T1    = (u16*)(ws + 0);        // wTqkv  [3072][1024]  0-6MB   (dead after gemm0)
    u16*   T2    = (u16*)(ws + 6  * MB);  // wTattn [1024][1024]  6-8MB   (dead after gemm1)
    u16*   T3    = (u16*)(ws + 8  * MB);  // wTff1  [4096][1024]  8-16MB  (dead after gemm2)
    u16*   T4    = (u16*)(ws + 16 * MB);  // wTff2  [1024][4096]  16-24MB (dead after gemm3)
    u16*   h1    = (u16*)(ws + 24 * MB);  // [2048][1024]         24-28MB (dead after gemm0)
    u16*   Qh    = (u16*)(ws + 28 * MB);  // [16][2048][64]       28-32MB (dead after attn)
    u16*   Kh    = (u16*)(ws + 32 * MB);  // [16][2048][64]       32-36MB (dead after attn)
    u16*   VT    = (u16*)(ws + 36 * MB);  // [16][64][2048]       36-40MB (dead after attn)
    u16*   Opart = (u16*)(ws + 40 * MB);  // bf16 [16][32][4][64][64] 40-56MB (dead after combine)
    float* mlbuf = (float*)(ws + 56 * MB);// f32  [16][32][4][64][2]  56-57MB
    u16*   att   = (u16*)(ws + 0);        // [2048][1024]         0-4MB  (T1 dead)
    float* x2    = (float*)(ws + 40 * MB);// f32 [2048][1024]     40-48MB (Opart dead; live to gemm3)
    u16*   h2    = (u16*)(ws + 4  * MB);  // [2048][1024]         4-8MB  (T2 dead)
    u16*   ff    = (u16*)(ws + 24 * MB);  // [2048][4096]         24-40MB (h1/Qh/Kh/VT dead)

    transall_k<<<3072, 256, 0, stream>>>(w_qkv, T1, w_attn, T2, w_ff1, T3, w_ff2, T4);
    ln_k<<<SEQ, 256, 0, stream>>>(x, ln1g, ln1b, h1);
    // QKV GEMM with fused RoPE + V-transpose epilogue
    gemm_k<64,128,2,2,4><<<dim3(32, 24), 256, 0, stream>>>(h1, T1, nullptr, nullptr, nullptr,
                                                           Qh, Kh, VT, SEQ, 3072, 1024);
    attn_k<<<dim3(32, 16, NCHUNK), 256, 0, stream>>>(Qh, Kh, VT, Opart, mlbuf);
    combine_k<<<dim3(32, 16), 256, 0, stream>>>(Opart, mlbuf, att);
    gemm_k<64,64,2,2,1><<<dim3(32, 16), 256, 0, stream>>>(att, T2, b_attn, x, x2,
                                                          nullptr, nullptr, nullptr, SEQ, 1024, 1024);
    ln_k<<<SEQ, 256, 0, stream>>>(x2, ln2g, ln2b, h2);
    gemm_k<64,128,1,4,2><<<dim3(32, 32), 256, 0, stream>>>(h2, T3, b_ff1, nullptr, ff,
                                                           nullptr, nullptr, nullptr, SEQ, 4096, 1024);
    gemm_k<64,64,2,2,3><<<dim3(32, 16), 256, 0, stream>>>(ff, T4, b_ff2, x2, (float*)d_out,
                                                          nullptr, nullptr, nullptr, SEQ, 1024, 4096);
}